// Round 9
// baseline (7387.342 us; speedup 1.0000x reference)
//
#include <hip/hip_runtime.h>

// HighwayLayerDiscrete: 256-step recurrent highway net, batch 64, units 1024.
// Step t: h1=lrelu(y@w_y+xp[t]); h2=lrelu(h1@Wh0+b0); h3=lrelu(h2@Wh1+b1);
// y += h3@w_out + b_out; out[:,t,:]=y.   u-recurrence (R12): u += h3@W2 + c2,
// h1' = lrelu(u + xp[t+1]), W2 = w_out@w_y (per-thread frags in w2reg).
//
// R16 = R12 (4.83 ms, PASSED) + WAVE-GRANULAR PHASES + SHUFFLE REDUCTION +
// DUAL j2.
// R15 post-mortem: 4 SEQUENTIAL polls/wave = 4 LLC RTs on the chain (+0.53
// us/phase). Fix: wave w needs only producers 4wq..4wq+3 (wq=(w+cg)&7) for
// its K-range [128wq,128wq+128) -> ONE 64-lane poll of those 4 flags, then
// wave stages its own 4KB slab (in-wave vmcnt+lgkmcnt ordering, NO stage
// barrier) and computes immediately. Straggler delays 1/8 of compute, not
// all of it.
// Reduction: 3-level __shfl_xor over the 8 same-ci lanes (sp differs in
// lane bits 3..5) -> red shrinks 64->8 slices (LDS traffic /8, finalize
// reads 8 not 64). Freed LDS -> red_y bank: j2 computes acc(W2)+accY(w_out)
// dual (reads A once), y-finalize runs on upper 256 lanes CONCURRENT with
// u-finalize -> R12's serial off-chain y block (compute+barrier+64-read
// reduce every 3rd phase) eliminated. 2 barriers/phase (pre-finalize,
// drain).
// Carried invariants: 256 coop blocks x 512 thr (R4); no cross-WG split-K
// (R2/R3); no cache fences (R1); sc1 device-scope exchange only (R10/R14:
// XCD-local abandoned after 2 hard failures); release = waitcnt0+barrier+
// flag; single vector poll (R15 lesson); per-producer flags, 512-uint
// footprint (R8/R10); finalize-operand prefetch (R8); K-retile 64x16,
// unique W frags (R9); LDS skew injective (R5); W2 prologue + 3-phase
// (R12); R11 cg mapping (W L2-resident).

constexpr int B = 64, T = 256, U = 1024, E = 512;
constexpr int BU = B * U;     // 65536
constexpr int APITCH = 1156;  // A-row pitch (1024 + 36-skew; ==4 mod 8)
constexpr int RPITCH = 264;   // red slice pitch (256 + 8)
constexpr int WOPITCH = 9;    // prologue w_out_s pitch

#define LRELU(v) ((v) > 0.f ? (v) : 0.2f * (v))

using f4 = float __attribute__((ext_vector_type(4)));

__device__ __forceinline__ void llc_store(float* p, float v) {
  __hip_atomic_store(p, v, __ATOMIC_RELAXED, __HIP_MEMORY_SCOPE_AGENT);
}
__device__ __forceinline__ unsigned llc_flag(const unsigned* p) {
  return __hip_atomic_load(p, __ATOMIC_RELAXED, __HIP_MEMORY_SCOPE_AGENT);
}
__device__ __forceinline__ void llc_post(unsigned* p, unsigned v) {
  __hip_atomic_store(p, v, __ATOMIC_RELAXED, __HIP_MEMORY_SCOPE_AGENT);
}

// 8x4x(K=16) tile from LDS a_s x register bank WB -> acc[8]
#define COMPUTE_ACC(WB)                                          \
  do {                                                           \
    _Pragma("unroll") for (int q = 0; q < 4; ++q) {              \
      const f4 w0 = WB[4 * q], w1 = WB[4 * q + 1];               \
      const f4 w2 = WB[4 * q + 2], w3 = WB[4 * q + 3];           \
      const int ab = abase_k + 4 * q;                            \
      _Pragma("unroll") for (int r = 0; r < 8; ++r) {            \
        f4 a = *(const f4*)&a_s[r * APITCH + ab];                \
        acc[r] += a.x * w0 + a.y * w1 + a.z * w2 + a.w * w3;     \
      }                                                          \
    }                                                            \
  } while (0)
// dual: read a once, two W banks (j2: W2 -> acc, w_out -> accY)
#define COMPUTE_DUAL(WBM, WBY)                                   \
  do {                                                           \
    _Pragma("unroll") for (int q = 0; q < 4; ++q) {              \
      const f4 m0 = WBM[4 * q], m1 = WBM[4 * q + 1];             \
      const f4 m2 = WBM[4 * q + 2], m3 = WBM[4 * q + 3];         \
      const f4 y0 = WBY[4 * q], y1 = WBY[4 * q + 1];             \
      const f4 y2 = WBY[4 * q + 2], y3 = WBY[4 * q + 3];         \
      const int ab = abase_k + 4 * q;                            \
      _Pragma("unroll") for (int r = 0; r < 8; ++r) {            \
        f4 a = *(const f4*)&a_s[r * APITCH + ab];                \
        acc[r] += a.x * m0 + a.y * m1 + a.z * m2 + a.w * m3;     \
        accY[r] += a.x * y0 + a.y * y1 + a.z * y2 + a.w * y3;    \
      }                                                          \
    }                                                            \
  } while (0)
// 3-level xor-shuffle reduce over lane bits 3..5 (the 8 sp-lanes per ci)
#define WAVE_REDUCE(ACC)                                         \
  do {                                                           \
    _Pragma("unroll") for (int r = 0; r < 8; ++r) {              \
      _Pragma("unroll") for (int c = 0; c < 4; ++c) {            \
        float v = ACC[r][c];                                     \
        v += __shfl_xor(v, 8, 64);                               \
        v += __shfl_xor(v, 16, 64);                              \
        v += __shfl_xor(v, 32, 64);                              \
        ACC[r][c] = v;                                           \
      }                                                          \
    }                                                            \
  } while (0)

// ---------------- init: zero flags ----------------
__global__ void k_init(unsigned* __restrict__ flags) {
  int tid = blockIdx.x * 256 + threadIdx.x;
  if (tid < 512) flags[tid] = 0u;
}

// ------- xproj[t*64+n][u] = emb[x[n][t]] @ w_x + b_in (R2/R3-proven) -------
__global__ __launch_bounds__(256) void k_xproj(
    const int* __restrict__ x, const float* __restrict__ emb,
    const float* __restrict__ w_x, const float* __restrict__ b_in,
    float* __restrict__ xp) {
  __shared__ float a_s[64][36];
  __shared__ float w_s[32][64];
  __shared__ int idxs[64];
  const int tid = threadIdx.x;
  const int m0 = blockIdx.x * 64;
  const int c0 = blockIdx.y * 64;
  if (tid < 64) {
    int m = m0 + tid;
    idxs[tid] = x[(m & 63) * T + (m >> 6)];  // x[n][t], row m = t*64+n
  }
  __syncthreads();
  const int rq = tid >> 4, cq = tid & 15;
  float acc[4][4] = {};
  for (int k0 = 0; k0 < E; k0 += 32) {
#pragma unroll
    for (int rep = 0; rep < 8; ++rep) {
      int e = rep * 256 + tid;
      int r = e >> 5, k = e & 31;
      a_s[r][k] = emb[(size_t)idxs[r] * E + k0 + k];
    }
#pragma unroll
    for (int rep = 0; rep < 2; ++rep) {
      int e = rep * 256 + tid;
      int kr = e >> 4, q = e & 15;
      *(float4*)&w_s[kr][4 * q] =
          *(const float4*)(w_x + (size_t)(k0 + kr) * U + c0 + 4 * q);
    }
    __syncthreads();
#pragma unroll
    for (int kc = 0; kc < 32; kc += 4) {
      float4 a4[4], w4[4];
#pragma unroll
      for (int i = 0; i < 4; ++i) a4[i] = *(const float4*)&a_s[4 * rq + i][kc];
#pragma unroll
      for (int kk = 0; kk < 4; ++kk)
        w4[kk] = *(const float4*)&w_s[kc + kk][4 * cq];
#pragma unroll
      for (int i = 0; i < 4; ++i) {
        const float av[4] = {a4[i].x, a4[i].y, a4[i].z, a4[i].w};
#pragma unroll
        for (int kk = 0; kk < 4; ++kk) {
          acc[i][0] += av[kk] * w4[kk].x;
          acc[i][1] += av[kk] * w4[kk].y;
          acc[i][2] += av[kk] * w4[kk].z;
          acc[i][3] += av[kk] * w4[kk].w;
        }
      }
    }
    __syncthreads();
  }
  const float4 bb = *(const float4*)(b_in + c0 + 4 * cq);
  const float bv[4] = {bb.x, bb.y, bb.z, bb.w};
#pragma unroll
  for (int i = 0; i < 4; ++i) {
    float4 o;
    o.x = acc[i][0] + bv[0];
    o.y = acc[i][1] + bv[1];
    o.z = acc[i][2] + bv[2];
    o.w = acc[i][3] + bv[3];
    *(float4*)(xp + (size_t)(m0 + 4 * rq + i) * U + c0 + 4 * cq) = o;
  }
}

// ---------------- sequential pipeline (wave-granular) ----------------
// 256 WGs. cg = (bid&7)*4 + ((bid>>3)&3), rg = bid>>5 (R11 mapping).
// Wave w computes K-range [128wq,128wq+128), wq=(w+cg)&7; thread
// (sp=8wq+(l>>3), ci=l&7): K-slice [16sp,+16), ALL 8 rows, cols 4ci..+4.
__global__ __launch_bounds__(512, 2) void k_seq(
    const float* __restrict__ xp, const float* __restrict__ w_y,
    const float* __restrict__ w_h, const float* __restrict__ b_h,
    const float* __restrict__ w_out, const float* __restrict__ b_out,
    const float* __restrict__ h0, float* __restrict__ out,
    float* __restrict__ slots, unsigned* __restrict__ flags) {
  __shared__ float a_s[8 * APITCH];     // 9248 floats
  __shared__ float red_u[8 * RPITCH];   // 2112 floats
  __shared__ float red_y[8 * RPITCH];   // 2112 floats
  __shared__ float c2_s[32], u0_s[32];
  const int tid = threadIdx.x;
  const int bid = blockIdx.x;
  const int cg = ((bid & 7) << 2) | ((bid >> 3) & 3);  // XCD-affine W slab
  const int rg = bid >> 5;
  const int w = tid >> 6, l = tid & 63;
  const int ci = l & 7;
  const int wq = (w + cg) & 7;       // K-block this wave owns (rotated)
  const int sp = 8 * wq + (l >> 3);  // K-slice in [0,64)
  const int cb = 4 * ci, k0 = 16 * sp;
  const int abase_k = 36 * (sp >> 1) + 16 * (sp & 1);
  // u-finalize coords (tid < 256)
  const int frow = 8 * rg + (tid >> 5);
  const int fu = 32 * cg + (tid & 31);
  // y-finalize coords (tid >= 256)
  const int ro2 = tid - 256;
  const int frow2 = 8 * rg + (ro2 >> 5);
  const int fu2 = 32 * cg + (ro2 & 31);
  // staging coords: lane l loads row l>>3, f4-col (l&7)+8i of its K-block
  const int srow = l >> 3;

  // ===== PROLOGUE (R12-proven): w2reg = frag of W2 = w_out@w_y; c2; u0 =====
  float* const wos = a_s;     // [1024][WOPITCH] = 9216 <= 9248, aliases a_s
  float* const wys = red_u;   // [8][36] = 288 <= 2112, aliases red_u
  f4 w2reg[16];
#pragma unroll
  for (int jj = 0; jj < 16; ++jj) w2reg[jj] = (f4){0.f, 0.f, 0.f, 0.f};
  f4 c2a = (f4){0.f, 0.f, 0.f, 0.f}, u0a = (f4){0.f, 0.f, 0.f, 0.f};
  {
    f4 nx0, nx1, nx2, nx3, nwy;
    {
      const float* wo = w_out + (size_t)tid * U;
      nx0 = *(const f4*)wo;
      nx1 = *(const f4*)(wo + 4);
      const float* wo2 = w_out + (size_t)(tid + 512) * U;
      nx2 = *(const f4*)wo2;
      nx3 = *(const f4*)(wo2 + 4);
      if (tid < 64)
        nwy = *(const f4*)(w_y + (size_t)(tid >> 3) * U + 32 * cg +
                           4 * (tid & 7));
    }
    for (int mi = 0; mi < 128; ++mi) {
      const int m0 = mi * 8;
#pragma unroll
      for (int q = 0; q < 4; ++q) {
        wos[tid * WOPITCH + q] = nx0[q];
        wos[tid * WOPITCH + 4 + q] = nx1[q];
        wos[(tid + 512) * WOPITCH + q] = nx2[q];
        wos[(tid + 512) * WOPITCH + 4 + q] = nx3[q];
      }
      if (tid < 64) *(f4*)&wys[(tid >> 3) * 36 + 4 * (tid & 7)] = nwy;
      __syncthreads();
      if (mi < 127) {
        const int m1 = m0 + 8;
        const float* wo = w_out + (size_t)tid * U + m1;
        nx0 = *(const f4*)wo;
        nx1 = *(const f4*)(wo + 4);
        const float* wo2 = w_out + (size_t)(tid + 512) * U + m1;
        nx2 = *(const f4*)wo2;
        nx3 = *(const f4*)(wo2 + 4);
        if (tid < 64)
          nwy = *(const f4*)(w_y + (size_t)(m1 + (tid >> 3)) * U + 32 * cg +
                             4 * (tid & 7));
      }
#pragma unroll
      for (int mm = 0; mm < 8; ++mm) {
        const f4 wy = *(const f4*)&wys[mm * 36 + cb];
#pragma unroll
        for (int jj = 0; jj < 16; ++jj)
          w2reg[jj] += wos[(16 * sp + jj) * WOPITCH + mm] * wy;
        if (tid < 8) {
          c2a += b_out[m0 + mm] * wy;
          u0a += h0[m0 + mm] * wy;
        }
      }
      __syncthreads();
    }
  }
  if (tid < 8) {
    *(f4*)&c2_s[cb] = c2a;
    *(f4*)&u0_s[cb] = u0a;
  }
  __syncthreads();
  // bootstrap: u (lower lanes), y (upper lanes); h1_0 -> slot0; post 1
  float u_reg = 0.f, y_reg = 0.f, c2_lane = 0.f;
  if (tid < 256) {
    c2_lane = c2_s[tid & 31];
    u_reg = u0_s[tid & 31];
    float h1 = LRELU(u_reg + xp[(size_t)frow * U + fu]);  // t=0
    llc_store(slots + (size_t)frow * U + fu, h1);         // slot0
  } else {
    y_reg = h0[fu2];
  }
  asm volatile("" ::: "memory");
  __builtin_amdgcn_s_waitcnt(0);
  __syncthreads();
  if (tid == 0) llc_post(&flags[rg * 32 + cg], 1u);

  // W prefetch for Q=1 (Wh0)
  f4 wreg[16];
  {
    const float* wp = w_h + (size_t)k0 * U + 32 * cg + cb;
#pragma unroll
    for (int jj = 0; jj < 16; ++jj)
      wreg[jj] = *(const f4*)(wp + (size_t)jj * U);
  }

  // ============ MAIN LOOP: 3 phases per step, wave-granular ============
  for (int Q = 1; Q <= 3 * T; ++Q) {
    const int j = (Q - 1) % 3, t = (Q - 1) / 3;
    const float* Asrc =
        slots + (size_t)((Q + 1) & 1) * BU + (size_t)(8 * rg) * U;
    float* slotw = slots + (size_t)(Q & 1) * BU;
    // ---- 1. finalize-operand prefetch (producer-independent; overlaps
    //         the poll spin) ----
    float preA = 0.f, preB = 0.f;
    if (tid < 256) {
      if (j == 0)
        preA = b_h[fu];
      else if (j == 1)
        preA = b_h[U + fu];
      else if (t < T - 1)
        preA = xp[((size_t)(t + 1) * B + frow) * U + fu];
    } else if (j == 2) {
      preB = b_out[fu2];
    }
    // ---- 2. per-wave poll: ONE 64-lane vector read of this wave's 4
    //         producer flags (R15 lesson: never sequential polls) ----
    {
      const unsigned* fp = &flags[rg * 32 + 4 * wq + (l & 3)];
      while (!__all(llc_flag(fp) >= (unsigned)Q)) __builtin_amdgcn_s_sleep(1);
    }
    asm volatile("" ::: "memory");
    // ---- 3. stage own 4KB slab: rows 0..7 x K[128wq,+128), in-wave
    //         ordering only (vmcnt then ds_write; no barrier) ----
    {
      const float* pb = Asrc + (size_t)srow * U + 128 * wq + cb;
      f4 s0, s1, s2, s3;
      asm volatile("global_load_dwordx4 %0, %1, off sc1"
                   : "=v"(s0) : "v"(pb));
      asm volatile("global_load_dwordx4 %0, %1, off sc1"
                   : "=v"(s1) : "v"(pb + 32));
      asm volatile("global_load_dwordx4 %0, %1, off sc1"
                   : "=v"(s2) : "v"(pb + 64));
      asm volatile("global_load_dwordx4 %0, %1, off sc1"
                   : "=v"(s3) : "v"(pb + 96));
      asm volatile("s_waitcnt vmcnt(0)" ::: "memory");
      const int db = srow * APITCH + 144 * wq + cb;  // 36*(4wq+i)+4ci
      *(f4*)&a_s[db] = s0;
      *(f4*)&a_s[db + 36] = s1;
      *(f4*)&a_s[db + 72] = s2;
      *(f4*)&a_s[db + 108] = s3;
    }
    // ---- 4. compute (reads only this wave's slab; compiler inserts
    //         lgkmcnt for the in-wave ds_write->ds_read dep) ----
    f4 acc[8], accY[8];
#pragma unroll
    for (int r = 0; r < 8; ++r) acc[r] = accY[r] = (f4){0.f, 0.f, 0.f, 0.f};
    if (j == 2)
      COMPUTE_DUAL(w2reg, wreg);  // wreg holds w_out at j2
    else
      COMPUTE_ACC(wreg);
    // ---- 5. in-wave shuffle reduce (8 sp-lanes -> 1) + slice write ----
    WAVE_REDUCE(acc);
    if (j == 2) WAVE_REDUCE(accY);
    if (l < 8) {
#pragma unroll
      for (int r = 0; r < 8; ++r)
        *(f4*)&red_u[w * RPITCH + r * 32 + 4 * l] = acc[r];
      if (j == 2) {
#pragma unroll
        for (int r = 0; r < 8; ++r)
          *(f4*)&red_y[w * RPITCH + r * 32 + 4 * l] = accY[r];
      }
    }
    __syncthreads();
    // ---- 6. finalize: u on lower 256 lanes, y on upper 256 (j2) ----
    if (tid < 256) {
      float s0 = red_u[0 * RPITCH + tid] + red_u[1 * RPITCH + tid];
      float s1 = red_u[2 * RPITCH + tid] + red_u[3 * RPITCH + tid];
      float s2 = red_u[4 * RPITCH + tid] + red_u[5 * RPITCH + tid];
      float s3 = red_u[6 * RPITCH + tid] + red_u[7 * RPITCH + tid];
      const float sum = (s0 + s1) + (s2 + s3);
      const size_t yi = (size_t)frow * U + fu;
      if (j < 2) {
        llc_store(slotw + yi, LRELU(sum + preA));  // h2 / h3
      } else {
        u_reg += sum + c2_lane;                      // u_{t+1}
        llc_store(slotw + yi, LRELU(u_reg + preA));  // h1_{t+1}
      }
    } else if (j == 2) {
      float s0 = red_y[0 * RPITCH + ro2] + red_y[1 * RPITCH + ro2];
      float s1 = red_y[2 * RPITCH + ro2] + red_y[3 * RPITCH + ro2];
      float s2 = red_y[4 * RPITCH + ro2] + red_y[5 * RPITCH + ro2];
      float s3 = red_y[6 * RPITCH + ro2] + red_y[7 * RPITCH + ro2];
      y_reg += (s0 + s1) + (s2 + s3) + preB;
    }
    // ---- 7. drain + release ----
    asm volatile("" ::: "memory");
    __builtin_amdgcn_s_waitcnt(0);
    __syncthreads();
    if (tid == 0) llc_post(&flags[rg * 32 + cg], (unsigned)(Q + 1));
    // ---- 8. deferred out store (j2, upper lanes; HBM ack off-chain) ----
    if (j == 2 && tid >= 256) out[((size_t)frow2 * T + t) * U + fu2] = y_reg;
    // ---- 9. W prefetch next phase: j0->Wh1, j1->w_out, j2->Wh0 ----
    if (Q < 3 * T) {
      const float* Wn = (j == 0)   ? (w_h + (size_t)U * U)
                        : (j == 1) ? w_out
                                   : w_h;
      const float* wp = Wn + (size_t)k0 * U + 32 * cg + cb;
#pragma unroll
      for (int jj = 0; jj < 16; ++jj)
        wreg[jj] = *(const f4*)(wp + (size_t)jj * U);
    }
  }
}

extern "C" void kernel_launch(void* const* d_in, const int* in_sizes, int n_in,
                              void* d_out, int out_size, void* d_ws,
                              size_t ws_size, hipStream_t stream) {
  const int* x = (const int*)d_in[0];
  const float* emb = (const float*)d_in[1];
  const float* w_y = (const float*)d_in[2];
  const float* w_x = (const float*)d_in[3];
  const float* b_in = (const float*)d_in[4];
  const float* w_h = (const float*)d_in[5];
  const float* b_h = (const float*)d_in[6];
  const float* w_out = (const float*)d_in[7];
  const float* b_out = (const float*)d_in[8];
  const float* h0 = (const float*)d_in[9];
  float* out = (float*)d_out;

  // workspace (floats): xproj | slots[2] | (dead) | flags — layout
  // IDENTICAL to R11/R12; footprint unchanged (R10 lesson).
  float* ws = (float*)d_ws;
  float* xpb = ws;                         // T*B*U
  float* slots = xpb + (size_t)T * B * U;  // 2*BU
  float* dead = slots + 2 * (size_t)BU;    // BU (unused)
  unsigned* flags = (unsigned*)(dead + (size_t)BU);  // 512 uints

  k_init<<<2, 256, 0, stream>>>(flags);
  dim3 g1(256, 16);
  k_xproj<<<g1, 256, 0, stream>>>(x, emb, w_x, b_in, xpb);

  void* args[] = {&xpb,   &w_y, &w_h, &b_h,   &w_out,
                  &b_out, &h0,  &out, &slots, &flags};
  hipLaunchCooperativeKernel((void*)k_seq, dim3(256), dim3(512), args, 0u,
                             stream);
}

// Round 10
// 7360.813 us; speedup vs baseline: 1.0036x; 1.0036x over previous
//
#include <hip/hip_runtime.h>

// HighwayLayerDiscrete: 256-step recurrent highway net, batch 64, units 1024.
// Step t: h1=lrelu(y@w_y+xp[t]); h2=lrelu(h1@Wh0+b0); h3=lrelu(h2@Wh1+b1);
// y += h3@w_out + b_out; out[:,t,:]=y.   u-recurrence (R12): u += h3@W2 + c2,
// h1' = lrelu(u + xp[t+1]), W2 = w_out@w_y (per-thread frags in w2reg).
//
// R17 = R16 + ONE change: dedicated wos LDS buffer -> total LDS ~91 KB >
// 80 KB -> 1 WG/CU FORCED.
// R16 post-mortem (+53%, FETCH/WRITE x4): R16 shrank LDS 104.9->54.3 KB,
// allowing 2 WGs/CU. Packing makes doubled-up WGs timeshare a CU; every
// phase waits for the slowest producer -> whole grid runs at packed speed
// (~2x). Packing also breaks bid->XCD affinity (W L2-residency) ->
// TCC-level traffic explosion. NEW INVARIANT: k_seq LDS must exceed 80 KB
// so exactly one WG fits per CU (R12's 104.9 KB was silently doing this).
// Carried from R16: wave-granular poll (ONE 64-lane read of the wave's 4
// producer flags — R15: never sequential), per-wave self-staged 4KB slab
// (in-wave vmcnt+lgkmcnt ordering, no stage barrier), 3-level __shfl_xor
// reduction (red 64->8 slices), dual-j2 (acc(W2)+accY(w_out) read A once;
// y-finalize on upper 256 lanes concurrent with u-finalize; out store
// deferred past the post). 2 barriers/phase.
// Carried invariants: 256 coop blocks x 512 thr (R4); no cross-WG split-K
// (R2/R3); no cache fences (R1); sc1 device-scope exchange only (R10/R14:
// XCD-local abandoned, 2 hard failures); release = waitcnt0+barrier+flag;
// per-producer flags, 512-uint footprint (R8/R10); finalize-operand
// prefetch (R8); K-retile 64x16, unique W frags (R9); LDS skew injective
// (R5); W2 prologue + 3-phase (R12); R11 cg mapping (W L2-resident).

constexpr int B = 64, T = 256, U = 1024, E = 512;
constexpr int BU = B * U;     // 65536
constexpr int APITCH = 1156;  // A-row pitch (1024 + 36-skew; ==4 mod 8)
constexpr int RPITCH = 264;   // red slice pitch (256 + 8)
constexpr int WOPITCH = 9;    // prologue w_out_s pitch

#define LRELU(v) ((v) > 0.f ? (v) : 0.2f * (v))

using f4 = float __attribute__((ext_vector_type(4)));

__device__ __forceinline__ void llc_store(float* p, float v) {
  __hip_atomic_store(p, v, __ATOMIC_RELAXED, __HIP_MEMORY_SCOPE_AGENT);
}
__device__ __forceinline__ unsigned llc_flag(const unsigned* p) {
  return __hip_atomic_load(p, __ATOMIC_RELAXED, __HIP_MEMORY_SCOPE_AGENT);
}
__device__ __forceinline__ void llc_post(unsigned* p, unsigned v) {
  __hip_atomic_store(p, v, __ATOMIC_RELAXED, __HIP_MEMORY_SCOPE_AGENT);
}

// 8x4x(K=16) tile from LDS a_s x register bank WB -> acc[8]
#define COMPUTE_ACC(WB)                                          \
  do {                                                           \
    _Pragma("unroll") for (int q = 0; q < 4; ++q) {              \
      const f4 w0 = WB[4 * q], w1 = WB[4 * q + 1];               \
      const f4 w2 = WB[4 * q + 2], w3 = WB[4 * q + 3];           \
      const int ab = abase_k + 4 * q;                            \
      _Pragma("unroll") for (int r = 0; r < 8; ++r) {            \
        f4 a = *(const f4*)&a_s[r * APITCH + ab];                \
        acc[r] += a.x * w0 + a.y * w1 + a.z * w2 + a.w * w3;     \
      }                                                          \
    }                                                            \
  } while (0)
// dual: read a once, two W banks (j2: W2 -> acc, w_out -> accY)
#define COMPUTE_DUAL(WBM, WBY)                                   \
  do {                                                           \
    _Pragma("unroll") for (int q = 0; q < 4; ++q) {              \
      const f4 m0 = WBM[4 * q], m1 = WBM[4 * q + 1];             \
      const f4 m2 = WBM[4 * q + 2], m3 = WBM[4 * q + 3];         \
      const f4 y0 = WBY[4 * q], y1 = WBY[4 * q + 1];             \
      const f4 y2 = WBY[4 * q + 2], y3 = WBY[4 * q + 3];         \
      const int ab = abase_k + 4 * q;                            \
      _Pragma("unroll") for (int r = 0; r < 8; ++r) {            \
        f4 a = *(const f4*)&a_s[r * APITCH + ab];                \
        acc[r] += a.x * m0 + a.y * m1 + a.z * m2 + a.w * m3;     \
        accY[r] += a.x * y0 + a.y * y1 + a.z * y2 + a.w * y3;    \
      }                                                          \
    }                                                            \
  } while (0)
// 3-level xor-shuffle reduce over lane bits 3..5 (the 8 sp-lanes per ci)
#define WAVE_REDUCE(ACC)                                         \
  do {                                                           \
    _Pragma("unroll") for (int r = 0; r < 8; ++r) {              \
      _Pragma("unroll") for (int c = 0; c < 4; ++c) {            \
        float v = ACC[r][c];                                     \
        v += __shfl_xor(v, 8, 64);                               \
        v += __shfl_xor(v, 16, 64);                              \
        v += __shfl_xor(v, 32, 64);                              \
        ACC[r][c] = v;                                           \
      }                                                          \
    }                                                            \
  } while (0)

// ---------------- init: zero flags ----------------
__global__ void k_init(unsigned* __restrict__ flags) {
  int tid = blockIdx.x * 256 + threadIdx.x;
  if (tid < 512) flags[tid] = 0u;
}

// ------- xproj[t*64+n][u] = emb[x[n][t]] @ w_x + b_in (R2/R3-proven) -------
__global__ __launch_bounds__(256) void k_xproj(
    const int* __restrict__ x, const float* __restrict__ emb,
    const float* __restrict__ w_x, const float* __restrict__ b_in,
    float* __restrict__ xp) {
  __shared__ float a_s[64][36];
  __shared__ float w_s[32][64];
  __shared__ int idxs[64];
  const int tid = threadIdx.x;
  const int m0 = blockIdx.x * 64;
  const int c0 = blockIdx.y * 64;
  if (tid < 64) {
    int m = m0 + tid;
    idxs[tid] = x[(m & 63) * T + (m >> 6)];  // x[n][t], row m = t*64+n
  }
  __syncthreads();
  const int rq = tid >> 4, cq = tid & 15;
  float acc[4][4] = {};
  for (int k0 = 0; k0 < E; k0 += 32) {
#pragma unroll
    for (int rep = 0; rep < 8; ++rep) {
      int e = rep * 256 + tid;
      int r = e >> 5, k = e & 31;
      a_s[r][k] = emb[(size_t)idxs[r] * E + k0 + k];
    }
#pragma unroll
    for (int rep = 0; rep < 2; ++rep) {
      int e = rep * 256 + tid;
      int kr = e >> 4, q = e & 15;
      *(float4*)&w_s[kr][4 * q] =
          *(const float4*)(w_x + (size_t)(k0 + kr) * U + c0 + 4 * q);
    }
    __syncthreads();
#pragma unroll
    for (int kc = 0; kc < 32; kc += 4) {
      float4 a4[4], w4[4];
#pragma unroll
      for (int i = 0; i < 4; ++i) a4[i] = *(const float4*)&a_s[4 * rq + i][kc];
#pragma unroll
      for (int kk = 0; kk < 4; ++kk)
        w4[kk] = *(const float4*)&w_s[kc + kk][4 * cq];
#pragma unroll
      for (int i = 0; i < 4; ++i) {
        const float av[4] = {a4[i].x, a4[i].y, a4[i].z, a4[i].w};
#pragma unroll
        for (int kk = 0; kk < 4; ++kk) {
          acc[i][0] += av[kk] * w4[kk].x;
          acc[i][1] += av[kk] * w4[kk].y;
          acc[i][2] += av[kk] * w4[kk].z;
          acc[i][3] += av[kk] * w4[kk].w;
        }
      }
    }
    __syncthreads();
  }
  const float4 bb = *(const float4*)(b_in + c0 + 4 * cq);
  const float bv[4] = {bb.x, bb.y, bb.z, bb.w};
#pragma unroll
  for (int i = 0; i < 4; ++i) {
    float4 o;
    o.x = acc[i][0] + bv[0];
    o.y = acc[i][1] + bv[1];
    o.z = acc[i][2] + bv[2];
    o.w = acc[i][3] + bv[3];
    *(float4*)(xp + (size_t)(m0 + 4 * rq + i) * U + c0 + 4 * cq) = o;
  }
}

// ---------------- sequential pipeline (wave-granular, 1 WG/CU) ------------
// 256 WGs. cg = (bid&7)*4 + ((bid>>3)&3), rg = bid>>5 (R11 mapping).
// Wave w computes K-range [128wq,128wq+128), wq=(w+cg)&7; thread
// (sp=8wq+(l>>3), ci=l&7): K-slice [16sp,+16), ALL 8 rows, cols 4ci..+4.
__global__ __launch_bounds__(512, 2) void k_seq(
    const float* __restrict__ xp, const float* __restrict__ w_y,
    const float* __restrict__ w_h, const float* __restrict__ b_h,
    const float* __restrict__ w_out, const float* __restrict__ b_out,
    const float* __restrict__ h0, float* __restrict__ out,
    float* __restrict__ slots, unsigned* __restrict__ flags) {
  __shared__ float a_s[8 * APITCH];        // 36992 B
  __shared__ float red_u[8 * RPITCH];      // 8448 B
  __shared__ float red_y[8 * RPITCH];      // 8448 B
  __shared__ float wos_s[1024 * WOPITCH];  // 36864 B (prologue; also the
                                           // >80KB occupancy pad: total
                                           // ~91KB -> 1 WG/CU FORCED)
  __shared__ float c2_s[32], u0_s[32];
  const int tid = threadIdx.x;
  const int bid = blockIdx.x;
  const int cg = ((bid & 7) << 2) | ((bid >> 3) & 3);  // XCD-affine W slab
  const int rg = bid >> 5;
  const int w = tid >> 6, l = tid & 63;
  const int ci = l & 7;
  const int wq = (w + cg) & 7;       // K-block this wave owns (rotated)
  const int sp = 8 * wq + (l >> 3);  // K-slice in [0,64)
  const int cb = 4 * ci, k0 = 16 * sp;
  const int abase_k = 36 * (sp >> 1) + 16 * (sp & 1);
  // u-finalize coords (tid < 256)
  const int frow = 8 * rg + (tid >> 5);
  const int fu = 32 * cg + (tid & 31);
  // y-finalize coords (tid >= 256)
  const int ro2 = tid - 256;
  const int frow2 = 8 * rg + (ro2 >> 5);
  const int fu2 = 32 * cg + (ro2 & 31);
  // staging coords: lane l loads row l>>3, f4-col (l&7)+8i of its K-block
  const int srow = l >> 3;

  // ===== PROLOGUE (R12-proven): w2reg = frag of W2 = w_out@w_y; c2; u0 =====
  float* const wos = wos_s;   // dedicated (de-aliased; occupancy pad)
  float* const wys = red_u;   // [8][36] = 288 <= 2112, aliases red_u
  f4 w2reg[16];
#pragma unroll
  for (int jj = 0; jj < 16; ++jj) w2reg[jj] = (f4){0.f, 0.f, 0.f, 0.f};
  f4 c2a = (f4){0.f, 0.f, 0.f, 0.f}, u0a = (f4){0.f, 0.f, 0.f, 0.f};
  {
    f4 nx0, nx1, nx2, nx3, nwy;
    {
      const float* wo = w_out + (size_t)tid * U;
      nx0 = *(const f4*)wo;
      nx1 = *(const f4*)(wo + 4);
      const float* wo2 = w_out + (size_t)(tid + 512) * U;
      nx2 = *(const f4*)wo2;
      nx3 = *(const f4*)(wo2 + 4);
      if (tid < 64)
        nwy = *(const f4*)(w_y + (size_t)(tid >> 3) * U + 32 * cg +
                           4 * (tid & 7));
    }
    for (int mi = 0; mi < 128; ++mi) {
      const int m0 = mi * 8;
#pragma unroll
      for (int q = 0; q < 4; ++q) {
        wos[tid * WOPITCH + q] = nx0[q];
        wos[tid * WOPITCH + 4 + q] = nx1[q];
        wos[(tid + 512) * WOPITCH + q] = nx2[q];
        wos[(tid + 512) * WOPITCH + 4 + q] = nx3[q];
      }
      if (tid < 64) *(f4*)&wys[(tid >> 3) * 36 + 4 * (tid & 7)] = nwy;
      __syncthreads();
      if (mi < 127) {
        const int m1 = m0 + 8;
        const float* wo = w_out + (size_t)tid * U + m1;
        nx0 = *(const f4*)wo;
        nx1 = *(const f4*)(wo + 4);
        const float* wo2 = w_out + (size_t)(tid + 512) * U + m1;
        nx2 = *(const f4*)wo2;
        nx3 = *(const f4*)(wo2 + 4);
        if (tid < 64)
          nwy = *(const f4*)(w_y + (size_t)(m1 + (tid >> 3)) * U + 32 * cg +
                             4 * (tid & 7));
      }
#pragma unroll
      for (int mm = 0; mm < 8; ++mm) {
        const f4 wy = *(const f4*)&wys[mm * 36 + cb];
#pragma unroll
        for (int jj = 0; jj < 16; ++jj)
          w2reg[jj] += wos[(16 * sp + jj) * WOPITCH + mm] * wy;
        if (tid < 8) {
          c2a += b_out[m0 + mm] * wy;
          u0a += h0[m0 + mm] * wy;
        }
      }
      __syncthreads();
    }
  }
  if (tid < 8) {
    *(f4*)&c2_s[cb] = c2a;
    *(f4*)&u0_s[cb] = u0a;
  }
  __syncthreads();
  // bootstrap: u (lower lanes), y (upper lanes); h1_0 -> slot0; post 1
  float u_reg = 0.f, y_reg = 0.f, c2_lane = 0.f;
  if (tid < 256) {
    c2_lane = c2_s[tid & 31];
    u_reg = u0_s[tid & 31];
    float h1 = LRELU(u_reg + xp[(size_t)frow * U + fu]);  // t=0
    llc_store(slots + (size_t)frow * U + fu, h1);         // slot0
  } else {
    y_reg = h0[fu2];
  }
  asm volatile("" ::: "memory");
  __builtin_amdgcn_s_waitcnt(0);
  __syncthreads();
  if (tid == 0) llc_post(&flags[rg * 32 + cg], 1u);

  // W prefetch for Q=1 (Wh0)
  f4 wreg[16];
  {
    const float* wp = w_h + (size_t)k0 * U + 32 * cg + cb;
#pragma unroll
    for (int jj = 0; jj < 16; ++jj)
      wreg[jj] = *(const f4*)(wp + (size_t)jj * U);
  }

  // ============ MAIN LOOP: 3 phases per step, wave-granular ============
  for (int Q = 1; Q <= 3 * T; ++Q) {
    const int j = (Q - 1) % 3, t = (Q - 1) / 3;
    const float* Asrc =
        slots + (size_t)((Q + 1) & 1) * BU + (size_t)(8 * rg) * U;
    float* slotw = slots + (size_t)(Q & 1) * BU;
    // ---- 1. finalize-operand prefetch (producer-independent; overlaps
    //         the poll spin) ----
    float preA = 0.f, preB = 0.f;
    if (tid < 256) {
      if (j == 0)
        preA = b_h[fu];
      else if (j == 1)
        preA = b_h[U + fu];
      else if (t < T - 1)
        preA = xp[((size_t)(t + 1) * B + frow) * U + fu];
    } else if (j == 2) {
      preB = b_out[fu2];
    }
    // ---- 2. per-wave poll: ONE 64-lane vector read of this wave's 4
    //         producer flags (R15 lesson: never sequential polls) ----
    {
      const unsigned* fp = &flags[rg * 32 + 4 * wq + (l & 3)];
      while (!__all(llc_flag(fp) >= (unsigned)Q)) __builtin_amdgcn_s_sleep(1);
    }
    asm volatile("" ::: "memory");
    // ---- 3. stage own 4KB slab: rows 0..7 x K[128wq,+128), in-wave
    //         ordering only (vmcnt then ds_write; no barrier) ----
    {
      const float* pb = Asrc + (size_t)srow * U + 128 * wq + cb;
      f4 s0, s1, s2, s3;
      asm volatile("global_load_dwordx4 %0, %1, off sc1"
                   : "=v"(s0) : "v"(pb));
      asm volatile("global_load_dwordx4 %0, %1, off sc1"
                   : "=v"(s1) : "v"(pb + 32));
      asm volatile("global_load_dwordx4 %0, %1, off sc1"
                   : "=v"(s2) : "v"(pb + 64));
      asm volatile("global_load_dwordx4 %0, %1, off sc1"
                   : "=v"(s3) : "v"(pb + 96));
      asm volatile("s_waitcnt vmcnt(0)" ::: "memory");
      const int db = srow * APITCH + 144 * wq + cb;  // 36*(4wq+i)+4ci
      *(f4*)&a_s[db] = s0;
      *(f4*)&a_s[db + 36] = s1;
      *(f4*)&a_s[db + 72] = s2;
      *(f4*)&a_s[db + 108] = s3;
    }
    // ---- 4. compute (reads only this wave's slab; compiler inserts
    //         lgkmcnt for the in-wave ds_write->ds_read dep) ----
    f4 acc[8], accY[8];
#pragma unroll
    for (int r = 0; r < 8; ++r) acc[r] = accY[r] = (f4){0.f, 0.f, 0.f, 0.f};
    if (j == 2)
      COMPUTE_DUAL(w2reg, wreg);  // wreg holds w_out at j2
    else
      COMPUTE_ACC(wreg);
    // ---- 5. in-wave shuffle reduce (8 sp-lanes -> 1) + slice write ----
    WAVE_REDUCE(acc);
    if (j == 2) WAVE_REDUCE(accY);
    if (l < 8) {
#pragma unroll
      for (int r = 0; r < 8; ++r)
        *(f4*)&red_u[w * RPITCH + r * 32 + 4 * l] = acc[r];
      if (j == 2) {
#pragma unroll
        for (int r = 0; r < 8; ++r)
          *(f4*)&red_y[w * RPITCH + r * 32 + 4 * l] = accY[r];
      }
    }
    __syncthreads();
    // ---- 6. finalize: u on lower 256 lanes, y on upper 256 (j2) ----
    if (tid < 256) {
      float s0 = red_u[0 * RPITCH + tid] + red_u[1 * RPITCH + tid];
      float s1 = red_u[2 * RPITCH + tid] + red_u[3 * RPITCH + tid];
      float s2 = red_u[4 * RPITCH + tid] + red_u[5 * RPITCH + tid];
      float s3 = red_u[6 * RPITCH + tid] + red_u[7 * RPITCH + tid];
      const float sum = (s0 + s1) + (s2 + s3);
      const size_t yi = (size_t)frow * U + fu;
      if (j < 2) {
        llc_store(slotw + yi, LRELU(sum + preA));  // h2 / h3
      } else {
        u_reg += sum + c2_lane;                      // u_{t+1}
        llc_store(slotw + yi, LRELU(u_reg + preA));  // h1_{t+1}
      }
    } else if (j == 2) {
      float s0 = red_y[0 * RPITCH + ro2] + red_y[1 * RPITCH + ro2];
      float s1 = red_y[2 * RPITCH + ro2] + red_y[3 * RPITCH + ro2];
      float s2 = red_y[4 * RPITCH + ro2] + red_y[5 * RPITCH + ro2];
      float s3 = red_y[6 * RPITCH + ro2] + red_y[7 * RPITCH + ro2];
      y_reg += (s0 + s1) + (s2 + s3) + preB;
    }
    // ---- 7. drain + release ----
    asm volatile("" ::: "memory");
    __builtin_amdgcn_s_waitcnt(0);
    __syncthreads();
    if (tid == 0) llc_post(&flags[rg * 32 + cg], (unsigned)(Q + 1));
    // ---- 8. deferred out store (j2, upper lanes; HBM ack off-chain) ----
    if (j == 2 && tid >= 256) out[((size_t)frow2 * T + t) * U + fu2] = y_reg;
    // ---- 9. W prefetch next phase: j0->Wh1, j1->w_out, j2->Wh0 ----
    if (Q < 3 * T) {
      const float* Wn = (j == 0)   ? (w_h + (size_t)U * U)
                        : (j == 1) ? w_out
                                   : w_h;
      const float* wp = Wn + (size_t)k0 * U + 32 * cg + cb;
#pragma unroll
      for (int jj = 0; jj < 16; ++jj)
        wreg[jj] = *(const f4*)(wp + (size_t)jj * U);
    }
  }
}

extern "C" void kernel_launch(void* const* d_in, const int* in_sizes, int n_in,
                              void* d_out, int out_size, void* d_ws,
                              size_t ws_size, hipStream_t stream) {
  const int* x = (const int*)d_in[0];
  const float* emb = (const float*)d_in[1];
  const float* w_y = (const float*)d_in[2];
  const float* w_x = (const float*)d_in[3];
  const float* b_in = (const float*)d_in[4];
  const float* w_h = (const float*)d_in[5];
  const float* b_h = (const float*)d_in[6];
  const float* w_out = (const float*)d_in[7];
  const float* b_out = (const float*)d_in[8];
  const float* h0 = (const float*)d_in[9];
  float* out = (float*)d_out;

  // workspace (floats): xproj | slots[2] | (dead) | flags — layout
  // IDENTICAL to R11/R12; footprint unchanged (R10 lesson).
  float* ws = (float*)d_ws;
  float* xpb = ws;                         // T*B*U
  float* slots = xpb + (size_t)T * B * U;  // 2*BU
  float* dead = slots + 2 * (size_t)BU;    // BU (unused)
  unsigned* flags = (unsigned*)(dead + (size_t)BU);  // 512 uints

  k_init<<<2, 256, 0, stream>>>(flags);
  dim3 g1(256, 16);
  k_xproj<<<g1, 256, 0, stream>>>(x, emb, w_x, b_in, xpb);

  void* args[] = {&xpb,   &w_y, &w_h, &b_h,   &w_out,
                  &b_out, &h0,  &out, &slots, &flags};
  hipLaunchCooperativeKernel((void*)k_seq, dim3(256), dim3(512), args, 0u,
                             stream);
}

// Round 11
// 6240.946 us; speedup vs baseline: 1.1837x; 1.1794x over previous
//
#include <hip/hip_runtime.h>

// HighwayLayerDiscrete: 256-step recurrent highway net, batch 64, units 1024.
// Step t: h1=lrelu(y@w_y+xp[t]); h2=lrelu(h1@Wh0+b0); h3=lrelu(h2@Wh1+b1);
// y += h3@w_out + b_out; out[:,t,:]=y.   u-recurrence (R12): u += h3@W2 + c2,
// h1' = lrelu(u + xp[t+1]), W2 = w_out@w_y (per-thread frags in w2reg).
//
// R18 = R16/R17 minus the REGISTER SPILL.
// R17 post-mortem: 1 WG/CU restored (LDS 91KB) yet dur + traffic unchanged
// -> occupancy theory dead. WRITE_SIZE 3.0GB = 11x actual store volume =
// SCRATCH traffic: dual-j2's accY pushed live regs (w2reg 64 + wreg 64 +
// acc 32 + accY 32 ~ 192) past the AGPR-assisted budget -> per-phase spill
// round trips on the chain (+3.4us/phase). NEW INVARIANT: at most ONE
// transient acc bank on top of the two persistent W banks (R12's proven
// pressure level).
// Kept from R16: wave-granular poll (ONE 64-lane read of the wave's 4
// producer flags; R15: never sequential), per-wave self-staged 4KB slab
// (in-wave vmcnt+lgkmcnt ordering, no stage barrier), 3-level __shfl_xor
// reduce (finalize reads 8 partials not 64), dedicated wos LDS buffer
// (total ~91KB > 80KB -> 1 WG/CU forced; R16's 54KB allowed 2 WG/CU
// packing). Dropped: dual-j2/accY — j2 y-matmul back to R12's off-chain
// block (after the post), REUSING acc; y-partials go to a dedicated red_y.
// Carried invariants: 256 coop blocks x 512 thr (R4); no cross-WG split-K
// (R2/R3); no cache fences (R1); sc1 device-scope exchange only (R10/R14:
// XCD-local abandoned, 2 hard failures); release = waitcnt0+barrier+flag;
// per-producer flags, 512-uint footprint (R8/R10); finalize-operand
// prefetch (R8); K-retile, unique W frags (R9); LDS skew injective (R5);
// W2 prologue + 3-phase (R12); R11 cg mapping (W L2-resident); k_seq LDS
// > 80KB (R16 lesson).

constexpr int B = 64, T = 256, U = 1024, E = 512;
constexpr int BU = B * U;     // 65536
constexpr int APITCH = 1156;  // A-row pitch (1024 + 36-skew; ==4 mod 8)
constexpr int RPITCH = 264;   // red slice pitch (256 + 8)
constexpr int WOPITCH = 9;    // prologue w_out_s pitch

#define LRELU(v) ((v) > 0.f ? (v) : 0.2f * (v))

using f4 = float __attribute__((ext_vector_type(4)));

__device__ __forceinline__ void llc_store(float* p, float v) {
  __hip_atomic_store(p, v, __ATOMIC_RELAXED, __HIP_MEMORY_SCOPE_AGENT);
}
__device__ __forceinline__ unsigned llc_flag(const unsigned* p) {
  return __hip_atomic_load(p, __ATOMIC_RELAXED, __HIP_MEMORY_SCOPE_AGENT);
}
__device__ __forceinline__ void llc_post(unsigned* p, unsigned v) {
  __hip_atomic_store(p, v, __ATOMIC_RELAXED, __HIP_MEMORY_SCOPE_AGENT);
}

// 8x4x(K=16) tile from LDS a_s x register bank WB -> acc[8]
#define COMPUTE_ACC(WB)                                          \
  do {                                                           \
    _Pragma("unroll") for (int r = 0; r < 8; ++r) acc[r] =       \
        (f4){0.f, 0.f, 0.f, 0.f};                                \
    _Pragma("unroll") for (int q = 0; q < 4; ++q) {              \
      const f4 w0 = WB[4 * q], w1 = WB[4 * q + 1];               \
      const f4 w2 = WB[4 * q + 2], w3 = WB[4 * q + 3];           \
      const int ab = abase_k + 4 * q;                            \
      _Pragma("unroll") for (int r = 0; r < 8; ++r) {            \
        f4 a = *(const f4*)&a_s[r * APITCH + ab];                \
        acc[r] += a.x * w0 + a.y * w1 + a.z * w2 + a.w * w3;     \
      }                                                          \
    }                                                            \
  } while (0)
// 3-level xor-shuffle reduce over lane bits 3..5 (the 8 sp-lanes per ci)
#define WAVE_REDUCE(ACC)                                         \
  do {                                                           \
    _Pragma("unroll") for (int r = 0; r < 8; ++r) {              \
      _Pragma("unroll") for (int c = 0; c < 4; ++c) {            \
        float v = ACC[r][c];                                     \
        v += __shfl_xor(v, 8, 64);                               \
        v += __shfl_xor(v, 16, 64);                              \
        v += __shfl_xor(v, 32, 64);                              \
        ACC[r][c] = v;                                           \
      }                                                          \
    }                                                            \
  } while (0)

// ---------------- init: zero flags ----------------
__global__ void k_init(unsigned* __restrict__ flags) {
  int tid = blockIdx.x * 256 + threadIdx.x;
  if (tid < 512) flags[tid] = 0u;
}

// ------- xproj[t*64+n][u] = emb[x[n][t]] @ w_x + b_in (R2/R3-proven) -------
__global__ __launch_bounds__(256) void k_xproj(
    const int* __restrict__ x, const float* __restrict__ emb,
    const float* __restrict__ w_x, const float* __restrict__ b_in,
    float* __restrict__ xp) {
  __shared__ float a_s[64][36];
  __shared__ float w_s[32][64];
  __shared__ int idxs[64];
  const int tid = threadIdx.x;
  const int m0 = blockIdx.x * 64;
  const int c0 = blockIdx.y * 64;
  if (tid < 64) {
    int m = m0 + tid;
    idxs[tid] = x[(m & 63) * T + (m >> 6)];  // x[n][t], row m = t*64+n
  }
  __syncthreads();
  const int rq = tid >> 4, cq = tid & 15;
  float acc[4][4] = {};
  for (int k0 = 0; k0 < E; k0 += 32) {
#pragma unroll
    for (int rep = 0; rep < 8; ++rep) {
      int e = rep * 256 + tid;
      int r = e >> 5, k = e & 31;
      a_s[r][k] = emb[(size_t)idxs[r] * E + k0 + k];
    }
#pragma unroll
    for (int rep = 0; rep < 2; ++rep) {
      int e = rep * 256 + tid;
      int kr = e >> 4, q = e & 15;
      *(float4*)&w_s[kr][4 * q] =
          *(const float4*)(w_x + (size_t)(k0 + kr) * U + c0 + 4 * q);
    }
    __syncthreads();
#pragma unroll
    for (int kc = 0; kc < 32; kc += 4) {
      float4 a4[4], w4[4];
#pragma unroll
      for (int i = 0; i < 4; ++i) a4[i] = *(const float4*)&a_s[4 * rq + i][kc];
#pragma unroll
      for (int kk = 0; kk < 4; ++kk)
        w4[kk] = *(const float4*)&w_s[kc + kk][4 * cq];
#pragma unroll
      for (int i = 0; i < 4; ++i) {
        const float av[4] = {a4[i].x, a4[i].y, a4[i].z, a4[i].w};
#pragma unroll
        for (int kk = 0; kk < 4; ++kk) {
          acc[i][0] += av[kk] * w4[kk].x;
          acc[i][1] += av[kk] * w4[kk].y;
          acc[i][2] += av[kk] * w4[kk].z;
          acc[i][3] += av[kk] * w4[kk].w;
        }
      }
    }
    __syncthreads();
  }
  const float4 bb = *(const float4*)(b_in + c0 + 4 * cq);
  const float bv[4] = {bb.x, bb.y, bb.z, bb.w};
#pragma unroll
  for (int i = 0; i < 4; ++i) {
    float4 o;
    o.x = acc[i][0] + bv[0];
    o.y = acc[i][1] + bv[1];
    o.z = acc[i][2] + bv[2];
    o.w = acc[i][3] + bv[3];
    *(float4*)(xp + (size_t)(m0 + 4 * rq + i) * U + c0 + 4 * cq) = o;
  }
}

// ---------------- sequential pipeline (wave-granular, 1 WG/CU) ------------
// 256 WGs. cg = (bid&7)*4 + ((bid>>3)&3), rg = bid>>5 (R11 mapping).
// Wave w computes K-range [128wq,128wq+128), wq=(w+cg)&7; thread
// (sp=8wq+(l>>3), ci=l&7): K-slice [16sp,+16), ALL 8 rows, cols 4ci..+4.
__global__ __launch_bounds__(512, 2) void k_seq(
    const float* __restrict__ xp, const float* __restrict__ w_y,
    const float* __restrict__ w_h, const float* __restrict__ b_h,
    const float* __restrict__ w_out, const float* __restrict__ b_out,
    const float* __restrict__ h0, float* __restrict__ out,
    float* __restrict__ slots, unsigned* __restrict__ flags) {
  __shared__ float a_s[8 * APITCH];        // 36992 B
  __shared__ float red_u[8 * RPITCH];      // 8448 B
  __shared__ float red_y[8 * RPITCH];      // 8448 B
  __shared__ float wos_s[1024 * WOPITCH];  // 36864 B (prologue; occupancy
                                           // pad: total ~91KB -> 1 WG/CU)
  __shared__ float c2_s[32], u0_s[32];
  const int tid = threadIdx.x;
  const int bid = blockIdx.x;
  const int cg = ((bid & 7) << 2) | ((bid >> 3) & 3);  // XCD-affine W slab
  const int rg = bid >> 5;
  const int w = tid >> 6, l = tid & 63;
  const int ci = l & 7;
  const int wq = (w + cg) & 7;       // K-block this wave owns (rotated)
  const int sp = 8 * wq + (l >> 3);  // K-slice in [0,64)
  const int cb = 4 * ci, k0 = 16 * sp;
  const int abase_k = 36 * (sp >> 1) + 16 * (sp & 1);
  // finalize-lane coords (valid for tid < 256)
  const int frow = 8 * rg + (tid >> 5);
  const int fu = 32 * cg + (tid & 31);
  // staging coords: lane l loads row l>>3, f4-col (l&7)+8i of its K-block
  const int srow = l >> 3;

  // ===== PROLOGUE (R12-proven): w2reg = frag of W2 = w_out@w_y; c2; u0 =====
  float* const wos = wos_s;  // dedicated (occupancy pad; R16 lesson)
  float* const wys = red_u;  // [8][36] = 288 <= 2112, aliases red_u
  f4 w2reg[16];
#pragma unroll
  for (int jj = 0; jj < 16; ++jj) w2reg[jj] = (f4){0.f, 0.f, 0.f, 0.f};
  f4 c2a = (f4){0.f, 0.f, 0.f, 0.f}, u0a = (f4){0.f, 0.f, 0.f, 0.f};
  {
    f4 nx0, nx1, nx2, nx3, nwy;
    {
      const float* wo = w_out + (size_t)tid * U;
      nx0 = *(const f4*)wo;
      nx1 = *(const f4*)(wo + 4);
      const float* wo2 = w_out + (size_t)(tid + 512) * U;
      nx2 = *(const f4*)wo2;
      nx3 = *(const f4*)(wo2 + 4);
      if (tid < 64)
        nwy = *(const f4*)(w_y + (size_t)(tid >> 3) * U + 32 * cg +
                           4 * (tid & 7));
    }
    for (int mi = 0; mi < 128; ++mi) {
      const int m0 = mi * 8;
#pragma unroll
      for (int q = 0; q < 4; ++q) {
        wos[tid * WOPITCH + q] = nx0[q];
        wos[tid * WOPITCH + 4 + q] = nx1[q];
        wos[(tid + 512) * WOPITCH + q] = nx2[q];
        wos[(tid + 512) * WOPITCH + 4 + q] = nx3[q];
      }
      if (tid < 64) *(f4*)&wys[(tid >> 3) * 36 + 4 * (tid & 7)] = nwy;
      __syncthreads();
      if (mi < 127) {
        const int m1 = m0 + 8;
        const float* wo = w_out + (size_t)tid * U + m1;
        nx0 = *(const f4*)wo;
        nx1 = *(const f4*)(wo + 4);
        const float* wo2 = w_out + (size_t)(tid + 512) * U + m1;
        nx2 = *(const f4*)wo2;
        nx3 = *(const f4*)(wo2 + 4);
        if (tid < 64)
          nwy = *(const f4*)(w_y + (size_t)(m1 + (tid >> 3)) * U + 32 * cg +
                             4 * (tid & 7));
      }
#pragma unroll
      for (int mm = 0; mm < 8; ++mm) {
        const f4 wy = *(const f4*)&wys[mm * 36 + cb];
#pragma unroll
        for (int jj = 0; jj < 16; ++jj)
          w2reg[jj] += wos[(16 * sp + jj) * WOPITCH + mm] * wy;
        if (tid < 8) {
          c2a += b_out[m0 + mm] * wy;
          u0a += h0[m0 + mm] * wy;
        }
      }
      __syncthreads();
    }
  }
  if (tid < 8) {
    *(f4*)&c2_s[cb] = c2a;
    *(f4*)&u0_s[cb] = u0a;
  }
  __syncthreads();
  // bootstrap: u,y registers; h1_0 -> slot0; release (post=1)
  float u_reg = 0.f, y_reg = 0.f, c2_lane = 0.f;
  if (tid < 256) {
    c2_lane = c2_s[tid & 31];
    u_reg = u0_s[tid & 31];
    y_reg = h0[fu];
    float h1 = LRELU(u_reg + xp[(size_t)frow * U + fu]);  // t=0
    llc_store(slots + (size_t)frow * U + fu, h1);         // slot0
  }
  asm volatile("" ::: "memory");
  __builtin_amdgcn_s_waitcnt(0);
  __syncthreads();
  if (tid == 0) llc_post(&flags[rg * 32 + cg], 1u);

  // W prefetch for Q=1 (Wh0)
  f4 wreg[16];
  {
    const float* wp = w_h + (size_t)k0 * U + 32 * cg + cb;
#pragma unroll
    for (int jj = 0; jj < 16; ++jj)
      wreg[jj] = *(const f4*)(wp + (size_t)jj * U);
  }

  // ============ MAIN LOOP: 3 phases per step, wave-granular ============
  for (int Q = 1; Q <= 3 * T; ++Q) {
    const int j = (Q - 1) % 3, t = (Q - 1) / 3;
    const float* Asrc =
        slots + (size_t)((Q + 1) & 1) * BU + (size_t)(8 * rg) * U;
    float* slotw = slots + (size_t)(Q & 1) * BU;
    // ---- 1. finalize-operand prefetch (producer-independent) ----
    float preA = 0.f, preB = 0.f;
    if (tid < 256) {
      if (j == 0)
        preA = b_h[fu];
      else if (j == 1)
        preA = b_h[U + fu];
      else {
        if (t < T - 1) preA = xp[((size_t)(t + 1) * B + frow) * U + fu];
        preB = b_out[fu];
      }
    }
    // ---- 2. per-wave poll: ONE 64-lane vector read of this wave's 4
    //         producer flags (R15 lesson: never sequential polls) ----
    {
      const unsigned* fp = &flags[rg * 32 + 4 * wq + (l & 3)];
      while (!__all(llc_flag(fp) >= (unsigned)Q)) __builtin_amdgcn_s_sleep(1);
    }
    asm volatile("" ::: "memory");
    // ---- 3. stage own 4KB slab: rows 0..7 x K[128wq,+128), in-wave
    //         ordering only (vmcnt then ds_write; no barrier) ----
    {
      const float* pb = Asrc + (size_t)srow * U + 128 * wq + cb;
      f4 s0, s1, s2, s3;
      asm volatile("global_load_dwordx4 %0, %1, off sc1"
                   : "=v"(s0) : "v"(pb));
      asm volatile("global_load_dwordx4 %0, %1, off sc1"
                   : "=v"(s1) : "v"(pb + 32));
      asm volatile("global_load_dwordx4 %0, %1, off sc1"
                   : "=v"(s2) : "v"(pb + 64));
      asm volatile("global_load_dwordx4 %0, %1, off sc1"
                   : "=v"(s3) : "v"(pb + 96));
      asm volatile("s_waitcnt vmcnt(0)" ::: "memory");
      const int db = srow * APITCH + 144 * wq + cb;  // 36*(4wq+i)+4ci
      *(f4*)&a_s[db] = s0;
      *(f4*)&a_s[db + 36] = s1;
      *(f4*)&a_s[db + 72] = s2;
      *(f4*)&a_s[db + 108] = s3;
    }
    // ---- 4. compute (reads only this wave's slab; in-wave lgkmcnt dep) --
    f4 acc[8];
    if (j == 2)
      COMPUTE_ACC(w2reg);
    else
      COMPUTE_ACC(wreg);
    // ---- 5. in-wave shuffle reduce (8 sp-lanes -> 1) + slice write ----
    WAVE_REDUCE(acc);
    if (l < 8) {
#pragma unroll
      for (int r = 0; r < 8; ++r)
        *(f4*)&red_u[w * RPITCH + r * 32 + 4 * l] = acc[r];
    }
    __syncthreads();
    // ---- 6. finalize: sum 8 wave-partials, update state, store h ----
    if (tid < 256) {
      float s0 = red_u[0 * RPITCH + tid] + red_u[1 * RPITCH + tid];
      float s1 = red_u[2 * RPITCH + tid] + red_u[3 * RPITCH + tid];
      float s2 = red_u[4 * RPITCH + tid] + red_u[5 * RPITCH + tid];
      float s3 = red_u[6 * RPITCH + tid] + red_u[7 * RPITCH + tid];
      const float sum = (s0 + s1) + (s2 + s3);
      const size_t yi = (size_t)frow * U + fu;
      if (j < 2) {
        llc_store(slotw + yi, LRELU(sum + preA));  // h2 / h3
      } else {
        u_reg += sum + c2_lane;                      // u_{t+1}
        llc_store(slotw + yi, LRELU(u_reg + preA));  // h1_{t+1}
      }
    }
    // ---- 7. drain + release ----
    asm volatile("" ::: "memory");
    __builtin_amdgcn_s_waitcnt(0);
    __syncthreads();
    if (tid == 0) llc_post(&flags[rg * 32 + cg], (unsigned)(Q + 1));
    // ---- 8. j==2 OFF-CHAIN: y += h3@w_out + b_out (REUSES acc; a_s slab
    //         is self-owned and untouched since step 4) ----
    if (j == 2) {
      COMPUTE_ACC(wreg);  // wreg holds w_out here
      WAVE_REDUCE(acc);
      if (l < 8) {
#pragma unroll
        for (int r = 0; r < 8; ++r)
          *(f4*)&red_y[w * RPITCH + r * 32 + 4 * l] = acc[r];
      }
      __syncthreads();
      if (tid < 256) {
        float s0 = red_y[0 * RPITCH + tid] + red_y[1 * RPITCH + tid];
        float s1 = red_y[2 * RPITCH + tid] + red_y[3 * RPITCH + tid];
        float s2 = red_y[4 * RPITCH + tid] + red_y[5 * RPITCH + tid];
        float s3 = red_y[6 * RPITCH + tid] + red_y[7 * RPITCH + tid];
        y_reg += (s0 + s1) + (s2 + s3) + preB;
        out[((size_t)frow * T + t) * U + fu] = y_reg;
      }
    }
    // ---- 9. W prefetch next phase: j0->Wh1, j1->w_out, j2->Wh0 ----
    if (Q < 3 * T) {
      const float* Wn = (j == 0)   ? (w_h + (size_t)U * U)
                        : (j == 1) ? w_out
                                   : w_h;
      const float* wp = Wn + (size_t)k0 * U + 32 * cg + cb;
#pragma unroll
      for (int jj = 0; jj < 16; ++jj)
        wreg[jj] = *(const f4*)(wp + (size_t)jj * U);
    }
  }
}

extern "C" void kernel_launch(void* const* d_in, const int* in_sizes, int n_in,
                              void* d_out, int out_size, void* d_ws,
                              size_t ws_size, hipStream_t stream) {
  const int* x = (const int*)d_in[0];
  const float* emb = (const float*)d_in[1];
  const float* w_y = (const float*)d_in[2];
  const float* w_x = (const float*)d_in[3];
  const float* b_in = (const float*)d_in[4];
  const float* w_h = (const float*)d_in[5];
  const float* b_h = (const float*)d_in[6];
  const float* w_out = (const float*)d_in[7];
  const float* b_out = (const float*)d_in[8];
  const float* h0 = (const float*)d_in[9];
  float* out = (float*)d_out;

  // workspace (floats): xproj | slots[2] | (dead) | flags — layout
  // IDENTICAL to R11/R12; footprint unchanged (R10 lesson).
  float* ws = (float*)d_ws;
  float* xpb = ws;                         // T*B*U
  float* slots = xpb + (size_t)T * B * U;  // 2*BU
  float* dead = slots + 2 * (size_t)BU;    // BU (unused)
  unsigned* flags = (unsigned*)(dead + (size_t)BU);  // 512 uints

  k_init<<<2, 256, 0, stream>>>(flags);
  dim3 g1(256, 16);
  k_xproj<<<g1, 256, 0, stream>>>(x, emb, w_x, b_in, xpb);

  void* args[] = {&xpb,   &w_y, &w_h, &b_h,   &w_out,
                  &b_out, &h0,  &out, &slots, &flags};
  hipLaunchCooperativeKernel((void*)k_seq, dim3(256), dim3(512), args, 0u,
                             stream);
}

// Round 12
// 4844.822 us; speedup vs baseline: 1.5248x; 1.2882x over previous
//
#include <hip/hip_runtime.h>

// HighwayLayerDiscrete: 256-step recurrent highway net, batch 64, units 1024.
// Reference step t: h1=lrelu(y@w_y+xp[t]); h2=lrelu(h1@Wh0+b0); h3=lrelu(h2@Wh1+b1);
// y += h3@w_out + b_out; out[:,t,:]=y.
//
// R19 = R12 VERBATIM REVERT (champion, 4.83 ms). R13-R18 post-mortems:
//  - R13 2-chain pipeline: +2.1us/superphase (2nd sync round on chain).
//  - R14 XCD-local sc0 exchange: deadlock (XCC_ID-derived grouping
//    unreliable in coop-launch context). ABANDONED (2 hard failures).
//  - R15 incremental staging: 4 SEQUENTIAL polls = 4 LLC RTs on chain.
//  - R16 wave-granular + dual-j2: 2 WG/CU packing (LDS 54KB) + spills.
//  - R17 (91KB LDS): spills persisted -> WRITE 3GB scratch traffic.
//  - R18 (no accY): traffic clean, STILL slower than R12 -> wave-granular
//    structure has negative value (pre-finalize barrier still gates on
//    slowest wave; 8x poll spin contends the flag lines with the posts).
// STRUCTURAL FLOOR (measured): 768 serial phases x (work ~2.2us + LLC
// protocol ~4.1us: store-ack 0.7 + post->detect 0.9 + stage RT/BW 1.0 +
// barriers/slop). Protocol latency is G16-mandated device-scope LLC RTs.
//
// R12 structure: phase Q=1..3T, j=(Q-1)%3. j0: h2=lrelu(h1@Wh0+b0);
// j1: h3=lrelu(h2@Wh1+b1); j2: u += h3@W2 + c2 (W2=w_out@w_y per-thread
// frags, prologue GEMM), h1'=lrelu(u+xp[t+1]); off-chain y += h3@w_out,
// out store. Carried invariants: 256 coop blocks x 512 thr (R4); no
// cross-WG split-K (R2/R3); no cache fences (R1); sc1 device-scope
// exchange; release = waitcnt0+barrier+flag; acquire = wave0 32-lane poll
// + barrier + clobber; per-producer flags, 512-uint footprint (R8/R10);
// finalize-operand prefetch (R8); K-retile 64x16, unique W frags,
// de-aliased red2 (R9); LDS skew injective (R5); LDS 104.9KB -> 1 WG/CU
// (R16 lesson); R11 cg mapping (W L2-resident under round-robin).

constexpr int B = 64, T = 256, U = 1024, E = 512;
constexpr int BU = B * U;     // 65536
constexpr int APITCH = 1156;  // A-row pitch (1024 + 36-skew; ==4 mod 8)
constexpr int RPITCH = 264;   // red2 slice pitch (256 + 8)
constexpr int WOPITCH = 9;    // prologue w_out_s pitch (odd -> 4-way max)

#define LRELU(v) ((v) > 0.f ? (v) : 0.2f * (v))

using f4 = float __attribute__((ext_vector_type(4)));

__device__ __forceinline__ void llc_store(float* p, float v) {
  __hip_atomic_store(p, v, __ATOMIC_RELAXED, __HIP_MEMORY_SCOPE_AGENT);
}
__device__ __forceinline__ unsigned llc_flag(const unsigned* p) {
  return __hip_atomic_load(p, __ATOMIC_RELAXED, __HIP_MEMORY_SCOPE_AGENT);
}
__device__ __forceinline__ void llc_post(unsigned* p, unsigned v) {
  __hip_atomic_store(p, v, __ATOMIC_RELAXED, __HIP_MEMORY_SCOPE_AGENT);
}

// 8x4x(K=32... K=16) tile from LDS a_s x register bank WB -> acc[8]
#define COMPUTE_ACC(WB)                                          \
  do {                                                           \
    _Pragma("unroll") for (int r = 0; r < 8; ++r) acc[r] =       \
        (f4){0.f, 0.f, 0.f, 0.f};                                \
    _Pragma("unroll") for (int q = 0; q < 4; ++q) {              \
      const f4 w0 = WB[4 * q], w1 = WB[4 * q + 1];               \
      const f4 w2 = WB[4 * q + 2], w3 = WB[4 * q + 3];           \
      const int ab = abase_k + 4 * q;                            \
      _Pragma("unroll") for (int r = 0; r < 8; ++r) {            \
        f4 a = *(const f4*)&a_s[r * APITCH + ab];                \
        acc[r] += a.x * w0 + a.y * w1 + a.z * w2 + a.w * w3;     \
      }                                                          \
    }                                                            \
  } while (0)

// ---------------- init: zero flags ----------------
__global__ void k_init(unsigned* __restrict__ flags) {
  int tid = blockIdx.x * 256 + threadIdx.x;
  if (tid < 512) flags[tid] = 0u;
}

// ------- xproj[t*64+n][u] = emb[x[n][t]] @ w_x + b_in (R2/R3-proven) -------
__global__ __launch_bounds__(256) void k_xproj(
    const int* __restrict__ x, const float* __restrict__ emb,
    const float* __restrict__ w_x, const float* __restrict__ b_in,
    float* __restrict__ xp) {
  __shared__ float a_s[64][36];
  __shared__ float w_s[32][64];
  __shared__ int idxs[64];
  const int tid = threadIdx.x;
  const int m0 = blockIdx.x * 64;
  const int c0 = blockIdx.y * 64;
  if (tid < 64) {
    int m = m0 + tid;
    idxs[tid] = x[(m & 63) * T + (m >> 6)];  // x[n][t], row m = t*64+n
  }
  __syncthreads();
  const int rq = tid >> 4, cq = tid & 15;
  float acc[4][4] = {};
  for (int k0 = 0; k0 < E; k0 += 32) {
#pragma unroll
    for (int rep = 0; rep < 8; ++rep) {
      int e = rep * 256 + tid;
      int r = e >> 5, k = e & 31;
      a_s[r][k] = emb[(size_t)idxs[r] * E + k0 + k];
    }
#pragma unroll
    for (int rep = 0; rep < 2; ++rep) {
      int e = rep * 256 + tid;
      int kr = e >> 4, q = e & 15;
      *(float4*)&w_s[kr][4 * q] =
          *(const float4*)(w_x + (size_t)(k0 + kr) * U + c0 + 4 * q);
    }
    __syncthreads();
#pragma unroll
    for (int kc = 0; kc < 32; kc += 4) {
      float4 a4[4], w4[4];
#pragma unroll
      for (int i = 0; i < 4; ++i) a4[i] = *(const float4*)&a_s[4 * rq + i][kc];
#pragma unroll
      for (int kk = 0; kk < 4; ++kk)
        w4[kk] = *(const float4*)&w_s[kc + kk][4 * cq];
#pragma unroll
      for (int i = 0; i < 4; ++i) {
        const float av[4] = {a4[i].x, a4[i].y, a4[i].z, a4[i].w};
#pragma unroll
        for (int kk = 0; kk < 4; ++kk) {
          acc[i][0] += av[kk] * w4[kk].x;
          acc[i][1] += av[kk] * w4[kk].y;
          acc[i][2] += av[kk] * w4[kk].z;
          acc[i][3] += av[kk] * w4[kk].w;
        }
      }
    }
    __syncthreads();
  }
  const float4 bb = *(const float4*)(b_in + c0 + 4 * cq);
  const float bv[4] = {bb.x, bb.y, bb.z, bb.w};
#pragma unroll
  for (int i = 0; i < 4; ++i) {
    float4 o;
    o.x = acc[i][0] + bv[0];
    o.y = acc[i][1] + bv[1];
    o.z = acc[i][2] + bv[2];
    o.w = acc[i][3] + bv[3];
    *(float4*)(xp + (size_t)(m0 + 4 * rq + i) * U + c0 + 4 * cq) = o;
  }
}

// ---------------- sequential pipeline ----------------
// 256 WGs. cg = (bid&7)*4 + ((bid>>3)&3), rg = bid>>5 (R11 mapping).
// Thread (s',ci): K-slice [16s',16s'+16), ALL 8 rows, cols [4ci,4ci+4) of 32.
// Phase Q=1..3T: j=(Q-1)%3 -> j0: h2=lrelu(h1@Wh0+b0); j1: h3=lrelu(h2@Wh1+b1);
// j2: u += h3@W2 + c2, store h1'=lrelu(u+xp[t+1]); off-chain y += h3@w_out.
__global__ __launch_bounds__(512, 2) void k_seq(
    const float* __restrict__ xp, const float* __restrict__ w_y,
    const float* __restrict__ w_h, const float* __restrict__ b_h,
    const float* __restrict__ w_out, const float* __restrict__ b_out,
    const float* __restrict__ h0, float* __restrict__ out,
    float* __restrict__ slots, unsigned* __restrict__ flags) {
  __shared__ float a_s[8 * APITCH];    // 9248 floats
  __shared__ float red2[64 * RPITCH];  // 16896 floats
  __shared__ float c2_s[32], u0_s[32];
  const int tid = threadIdx.x;
  const int bid = blockIdx.x;
  const int cg = ((bid & 7) << 2) | ((bid >> 3) & 3);  // XCD-affine W slab
  const int rg = bid >> 5;
  const int w = tid >> 6, l = tid & 63;
  const int ci = l & 7;
  const int sp = w * 8 + (l >> 3);  // s' in [0,64)
  const int cb = 4 * ci, k0 = 16 * sp;
  const int abase_k = 36 * (sp >> 1) + 16 * (sp & 1);  // skewed k0 offset
  // finalize-lane coords (valid for tid < 256)
  const int frow = 8 * rg + (tid >> 5);
  const int fu = 32 * cg + (tid & 31);
  // staging coords: row set {tb, tb+2, tb+4, tb+6}, rotated k start
  const int tb = tid >> 8;                      // 0 or 1
  const int kq = ((tid & 255) + 8 * cg) & 255;  // f4-unit index, cg-rotated
  const int lofs = 36 * (kq >> 3) + ((4 * kq) & 31);  // skewed LDS k-offset

  // ============ PROLOGUE: w2reg = per-thread fragment of W2 = w_out@w_y,
  // c2 = b_out@w_y, u0 = h0@w_y (cols 32cg..+32). Redundant per WG; LDS
  // staging aliases red2 (w_out_s[1024][9]) and a_s (wy_s[8][36]). ~130us.
  float* const wos = red2;  // [1024][WOPITCH]
  float* const wys = a_s;   // [8][36]
  f4 w2reg[16];
#pragma unroll
  for (int jj = 0; jj < 16; ++jj) w2reg[jj] = (f4){0.f, 0.f, 0.f, 0.f};
  f4 c2a = (f4){0.f, 0.f, 0.f, 0.f}, u0a = (f4){0.f, 0.f, 0.f, 0.f};
  {
    // reg double-buffer for w_out rows (tid, tid+512) x 8 m-cols
    f4 nx0, nx1, nx2, nx3, nwy;
    {
      const float* wo = w_out + (size_t)tid * U;
      nx0 = *(const f4*)wo;
      nx1 = *(const f4*)(wo + 4);
      const float* wo2 = w_out + (size_t)(tid + 512) * U;
      nx2 = *(const f4*)wo2;
      nx3 = *(const f4*)(wo2 + 4);
      if (tid < 64)
        nwy = *(const f4*)(w_y + (size_t)(tid >> 3) * U + 32 * cg +
                           4 * (tid & 7));
    }
    for (int mi = 0; mi < 128; ++mi) {
      const int m0 = mi * 8;
      // LDS write current chunk
#pragma unroll
      for (int q = 0; q < 4; ++q) {
        wos[tid * WOPITCH + q] = nx0[q];
        wos[tid * WOPITCH + 4 + q] = nx1[q];
        wos[(tid + 512) * WOPITCH + q] = nx2[q];
        wos[(tid + 512) * WOPITCH + 4 + q] = nx3[q];
      }
      if (tid < 64) *(f4*)&wys[(tid >> 3) * 36 + 4 * (tid & 7)] = nwy;
      __syncthreads();
      // issue next chunk loads (latency hides under compute)
      if (mi < 127) {
        const int m1 = m0 + 8;
        const float* wo = w_out + (size_t)tid * U + m1;
        nx0 = *(const f4*)wo;
        nx1 = *(const f4*)(wo + 4);
        const float* wo2 = w_out + (size_t)(tid + 512) * U + m1;
        nx2 = *(const f4*)wo2;
        nx3 = *(const f4*)(wo2 + 4);
        if (tid < 64)
          nwy = *(const f4*)(w_y + (size_t)(m1 + (tid >> 3)) * U + 32 * cg +
                             4 * (tid & 7));
      }
#pragma unroll
      for (int mm = 0; mm < 8; ++mm) {
        const f4 wy = *(const f4*)&wys[mm * 36 + cb];
#pragma unroll
        for (int jj = 0; jj < 16; ++jj)
          w2reg[jj] += wos[(16 * sp + jj) * WOPITCH + mm] * wy;
        if (tid < 8) {  // sp==0 lanes: c2/u0 accumulation
          c2a += b_out[m0 + mm] * wy;
          u0a += h0[m0 + mm] * wy;
        }
      }
      __syncthreads();
    }
  }
  if (tid < 8) {
    *(f4*)&c2_s[cb] = c2a;
    *(f4*)&u0_s[cb] = u0a;
  }
  __syncthreads();
  // bootstrap: u,y registers; h1_0 -> slot0; release (post=1)
  float u_reg = 0.f, y_reg = 0.f, c2_lane = 0.f;
  if (tid < 256) {
    c2_lane = c2_s[tid & 31];
    u_reg = u0_s[tid & 31];
    y_reg = h0[fu];
    float h1 = LRELU(u_reg + xp[(size_t)frow * U + fu]);  // t=0
    llc_store(slots + (size_t)frow * U + fu, h1);         // slot0
  }
  asm volatile("" ::: "memory");
  __builtin_amdgcn_s_waitcnt(0);
  __syncthreads();
  if (tid == 0) llc_post(&flags[rg * 32 + cg], 1u);

  // W prefetch for Q=1 (Wh0)
  f4 wreg[16];
  {
    const float* wp = w_h + (size_t)k0 * U + 32 * cg + cb;
#pragma unroll
    for (int jj = 0; jj < 16; ++jj) wreg[jj] = *(const f4*)(wp + (size_t)jj * U);
  }

  // ============ MAIN LOOP: 3 phases per step ============
  for (int Q = 1; Q <= 3 * T; ++Q) {
    const int j = (Q - 1) % 3, t = (Q - 1) / 3;
    const float* Asrc =
        slots + (size_t)((Q + 1) & 1) * BU + (size_t)(8 * rg) * U;
    float* slotw = slots + (size_t)(Q & 1) * BU;
    // ---- 1. poll: wave0 vector-reads all 32 per-producer flags ----
    if (tid < 64) {
      const unsigned tgt = (unsigned)Q;
      const unsigned* fp = &flags[rg * 32 + (l & 31)];
      while (!__all(llc_flag(fp) >= tgt)) __builtin_amdgcn_s_sleep(1);
    }
    __syncthreads();
    asm volatile("" ::: "memory");
    // ---- 1b. finalize-operand prefetch (off the producer tail) ----
    float preA = 0.f, preB = 0.f;
    if (tid < 256) {
      if (j == 0)
        preA = b_h[fu];
      else if (j == 1)
        preA = b_h[U + fu];
      else {
        if (t < T - 1) preA = xp[((size_t)(t + 1) * B + frow) * U + fu];
        preB = b_out[fu];
      }
    }
    // ---- 2. stage A: 8 rows x 1024 floats, b128 sc1 loads, cg-rotated ----
    {
      const float* pb = Asrc + 4 * kq;
      f4 av0, av1, av2, av3;
      asm volatile("global_load_dwordx4 %0, %1, off sc1"
                   : "=v"(av0)
                   : "v"(pb + (size_t)tb * U));
      asm volatile("global_load_dwordx4 %0, %1, off sc1"
                   : "=v"(av1)
                   : "v"(pb + (size_t)(tb + 2) * U));
      asm volatile("global_load_dwordx4 %0, %1, off sc1"
                   : "=v"(av2)
                   : "v"(pb + (size_t)(tb + 4) * U));
      asm volatile("global_load_dwordx4 %0, %1, off sc1"
                   : "=v"(av3)
                   : "v"(pb + (size_t)(tb + 6) * U));
      asm volatile("s_waitcnt vmcnt(0)" ::: "memory");
      *(f4*)&a_s[(tb + 0) * APITCH + lofs] = av0;
      *(f4*)&a_s[(tb + 2) * APITCH + lofs] = av1;
      *(f4*)&a_s[(tb + 4) * APITCH + lofs] = av2;
      *(f4*)&a_s[(tb + 6) * APITCH + lofs] = av3;
    }
    __syncthreads();
    // ---- 3. on-chain matmul: Wh0/Wh1 from wreg, W2 from persistent regs ----
    f4 acc[8];
    if (j == 2)
      COMPUTE_ACC(w2reg);
    else
      COMPUTE_ACC(wreg);
#pragma unroll
    for (int r = 0; r < 8; ++r)
      *(f4*)&red2[sp * RPITCH + r * 32 + cb] = acc[r];
    __syncthreads();
    // ---- 4. finalize: sum 64 partials, update state, store exchange ----
    if (tid < 256) {
      float s0 = 0.f, s1 = 0.f, s2 = 0.f, s3 = 0.f;
#pragma unroll
      for (int z = 0; z < 64; z += 4) {
        s0 += red2[(z + 0) * RPITCH + tid];
        s1 += red2[(z + 1) * RPITCH + tid];
        s2 += red2[(z + 2) * RPITCH + tid];
        s3 += red2[(z + 3) * RPITCH + tid];
      }
      const float sum = (s0 + s1) + (s2 + s3);
      const size_t yi = (size_t)frow * U + fu;
      if (j < 2) {
        llc_store(slotw + yi, LRELU(sum + preA));  // h2 / h3
      } else {
        u_reg += sum + c2_lane;                    // u_{t+1}
        llc_store(slotw + yi, LRELU(u_reg + preA));  // h1_{t+1}
      }
    }
    // ---- 5. drain + release ----
    asm volatile("" ::: "memory");
    __builtin_amdgcn_s_waitcnt(0);
    __syncthreads();
    if (tid == 0) llc_post(&flags[rg * 32 + cg], (unsigned)(Q + 1));
    // ---- 6. j==2 OFF-CHAIN: y += h3@w_out + b_out; out[:,t,:] = y ----
    if (j == 2) {
      f4 acc2[8];
      {
        f4* acc = acc2;  // reuse macro
        if (true) COMPUTE_ACC(wreg);  // wreg holds w_out here
      }
#pragma unroll
      for (int r = 0; r < 8; ++r)
        *(f4*)&red2[sp * RPITCH + r * 32 + cb] = acc2[r];
      __syncthreads();
      if (tid < 256) {
        float s0 = 0.f, s1 = 0.f, s2 = 0.f, s3 = 0.f;
#pragma unroll
        for (int z = 0; z < 64; z += 4) {
          s0 += red2[(z + 0) * RPITCH + tid];
          s1 += red2[(z + 1) * RPITCH + tid];
          s2 += red2[(z + 2) * RPITCH + tid];
          s3 += red2[(z + 3) * RPITCH + tid];
        }
        y_reg += (s0 + s1) + (s2 + s3) + preB;
        out[((size_t)frow * T + t) * U + fu] = y_reg;
      }
    }
    // ---- 7. W prefetch for next phase: j0->Wh1, j1->w_out, j2->Wh0 ----
    if (Q < 3 * T) {
      const float* Wn = (j == 0) ? (w_h + (size_t)U * U)
                       : (j == 1) ? w_out
                                  : w_h;
      const float* wp = Wn + (size_t)k0 * U + 32 * cg + cb;
#pragma unroll
      for (int jj = 0; jj < 16; ++jj)
        wreg[jj] = *(const f4*)(wp + (size_t)jj * U);
    }
  }
}

extern "C" void kernel_launch(void* const* d_in, const int* in_sizes, int n_in,
                              void* d_out, int out_size, void* d_ws,
                              size_t ws_size, hipStream_t stream) {
  const int* x = (const int*)d_in[0];
  const float* emb = (const float*)d_in[1];
  const float* w_y = (const float*)d_in[2];
  const float* w_x = (const float*)d_in[3];
  const float* b_in = (const float*)d_in[4];
  const float* w_h = (const float*)d_in[5];
  const float* b_h = (const float*)d_in[6];
  const float* w_out = (const float*)d_in[7];
  const float* b_out = (const float*)d_in[8];
  const float* h0 = (const float*)d_in[9];
  float* out = (float*)d_out;

  // workspace (floats): xproj | slots[2] | (dead ybuf slot) | flags
  // layout IDENTICAL to R11/R12 — footprint unchanged (R10 lesson).
  float* ws = (float*)d_ws;
  float* xpb = ws;                         // T*B*U
  float* slots = xpb + (size_t)T * B * U;  // 2*BU
  float* ybuf_dead = slots + 2 * (size_t)BU;         // BU (unused)
  unsigned* flags = (unsigned*)(ybuf_dead + (size_t)BU);  // 512 uints

  k_init<<<2, 256, 0, stream>>>(flags);
  dim3 g1(256, 16);
  k_xproj<<<g1, 256, 0, stream>>>(x, emb, w_x, b_in, xpb);

  void* args[] = {&xpb,  &w_y,   &w_h, &b_h,   &w_out,
                  &b_out, &h0,   &out, &slots, &flags};
  hipLaunchCooperativeKernel((void*)k_seq, dim3(256), dim3(512), args, 0u,
                             stream);
}